// Round 1
// baseline (704.973 us; speedup 1.0000x reference)
//
#include <hip/hip_runtime.h>
#include <hip/hip_bf16.h>

#define T_TOK 2048
#define D_DIM 2048
#define N_EXP 8
#define F_DIM 1024

typedef __attribute__((ext_vector_type(8))) short short8;
typedef __attribute__((ext_vector_type(4))) float floatx4;

__device__ __forceinline__ short f2bf(float f) {
  union { float f; unsigned u; } v; v.f = f;
  unsigned r = v.u + 0x7fffu + ((v.u >> 16) & 1u);
  return (short)(r >> 16);
}

__device__ __forceinline__ floatx4 mfma16(short8 a, short8 b, floatx4 c) {
  return __builtin_amdgcn_mfma_f32_16x16x32_bf16(a, b, c, 0, 0, 0);
}

// ---------------- transpose + fp32->bf16 convert: dst[c][r] = src[r][c] per expert ----
__global__ __launch_bounds__(256) void transpose_cvt(const float* __restrict__ src,
                                                     short* __restrict__ dst,
                                                     int R, int C) {
  __shared__ float tile[32][33];
  int e = blockIdx.z;
  src += (size_t)e * R * C;
  dst += (size_t)e * R * C;
  int c0 = blockIdx.x * 32, r0 = blockIdx.y * 32;
  int tx = threadIdx.x & 31, ty = threadIdx.x >> 5;
#pragma unroll
  for (int i = 0; i < 32; i += 8)
    tile[ty + i][tx] = src[(size_t)(r0 + ty + i) * C + c0 + tx];
  __syncthreads();
#pragma unroll
  for (int i = 0; i < 32; i += 8)
    dst[(size_t)(c0 + ty + i) * R + r0 + tx] = f2bf(tile[tx][ty + i]);
}

// ---------------- router: logits (fp32), top-2, expert lists, x -> bf16 --------------
__global__ __launch_bounds__(256) void router_kernel(
    const float* __restrict__ x, const float* __restrict__ gate_w,
    short* __restrict__ x_bf, float* __restrict__ out_logits,
    int* __restrict__ counts, int* __restrict__ tok_ids, float* __restrict__ tok_wts) {
  int t = blockIdx.x;
  int tid = threadIdx.x;
  const float* xr = x + (size_t)t * D_DIM + tid * 8;
  floatx4 xv0 = *(const floatx4*)xr;
  floatx4 xv1 = *(const floatx4*)(xr + 4);
  float xs[8];
#pragma unroll
  for (int j = 0; j < 4; j++) { xs[j] = xv0[j]; xs[4 + j] = xv1[j]; }
  union { short8 v; short s[8]; } xb;
#pragma unroll
  for (int j = 0; j < 8; j++) xb.s[j] = f2bf(xs[j]);
  *(short8*)(x_bf + (size_t)t * D_DIM + tid * 8) = xb.v;

  float p[N_EXP];
#pragma unroll
  for (int e = 0; e < N_EXP; e++) {
    const float* gw = gate_w + (size_t)e * D_DIM + tid * 8;
    floatx4 g0 = *(const floatx4*)gw;
    floatx4 g1 = *(const floatx4*)(gw + 4);
    float s = 0.f;
#pragma unroll
    for (int j = 0; j < 4; j++) s += xs[j] * g0[j] + xs[4 + j] * g1[j];
    p[e] = s;
  }
  __shared__ float red[N_EXP * 4];
  __shared__ float slog[N_EXP];
  int lane = tid & 63, wv = tid >> 6;
#pragma unroll
  for (int e = 0; e < N_EXP; e++) {
    float v = p[e];
#pragma unroll
    for (int off = 32; off > 0; off >>= 1) v += __shfl_down(v, off);
    if (lane == 0) red[e * 4 + wv] = v;
  }
  __syncthreads();
  if (tid < N_EXP) {
    float s = red[tid * 4] + red[tid * 4 + 1] + red[tid * 4 + 2] + red[tid * 4 + 3];
    slog[tid] = s;
    out_logits[(size_t)t * N_EXP + tid] = s;
  }
  __syncthreads();
  if (tid == 0) {
    float l[N_EXP];
#pragma unroll
    for (int e = 0; e < N_EXP; e++) l[e] = slog[e];
    int e0 = 0;
#pragma unroll
    for (int e = 1; e < N_EXP; e++) if (l[e] > l[e0]) e0 = e;
    int e1 = (e0 == 0) ? 1 : 0;
#pragma unroll
    for (int e = 0; e < N_EXP; e++) if (e != e0 && l[e] > l[e1]) e1 = e;
    float p1 = __expf(l[e1] - l[e0]);
    float s = 1.f + p1;
    int pos0 = atomicAdd(&counts[e0], 1);
    tok_ids[e0 * T_TOK + pos0] = t;             // k = 0
    tok_wts[e0 * T_TOK + pos0] = 1.f / s;
    int pos1 = atomicAdd(&counts[e1], 1);
    tok_ids[e1 * T_TOK + pos1] = t | (1 << 16); // k = 1
    tok_wts[e1 * T_TOK + pos1] = p1 / s;
  }
}

// ---------------- GEMM1: h[token,k][f] = silu(x Wg) * (x Wu) * route_w ---------------
__global__ __launch_bounds__(256) void gemm1_kernel(
    const short* __restrict__ x_bf,
    const short* __restrict__ wgT, const short* __restrict__ wuT,
    const int* __restrict__ counts, const int* __restrict__ tok_ids,
    const float* __restrict__ tok_wts,
    short* __restrict__ hbuf) {
  int e = blockIdx.x >> 5;
  int mt = blockIdx.x & 31;
  int count = counts[e];
  if (mt * 64 >= count) return;
  int f0 = blockIdx.y * 64;

  __shared__ short sA[64 * 40];
  __shared__ short sBg[64 * 40];
  __shared__ short sBu[64 * 40];
  __shared__ int s_tok[64];
  __shared__ float s_wt[64];

  int tid = threadIdx.x;
  if (tid < 64) {
    int r = mt * 64 + tid;
    if (r < count) {
      s_tok[tid] = tok_ids[e * T_TOK + r];
      s_wt[tid] = tok_wts[e * T_TOK + r];
    } else { s_tok[tid] = 0; s_wt[tid] = 0.f; }
  }
  int r4 = tid >> 2, ch = tid & 3;
  int lane = tid & 63, wv = tid >> 6;
  int wr = wv >> 1, wc = wv & 1;
  int qd = lane >> 4, l16 = lane & 15;

  floatx4 accG[2][2] = {};
  floatx4 accU[2][2] = {};
  __syncthreads();
  int raw = s_tok[r4];
  int tokr = raw & 0xFFFF;
  const short* xa  = x_bf + (size_t)tokr * D_DIM + ch * 8;
  const short* wga = wgT + ((size_t)e * F_DIM + f0 + r4) * D_DIM + ch * 8;
  const short* wua = wuT + ((size_t)e * F_DIM + f0 + r4) * D_DIM + ch * 8;
  short* wA  = sA  + r4 * 40 + ch * 8;
  short* wBg = sBg + r4 * 40 + ch * 8;
  short* wBu = sBu + r4 * 40 + ch * 8;
  const short* rA0  = sA  + (wr * 32 + l16) * 40 + qd * 8;
  const short* rBg0 = sBg + (wc * 32 + l16) * 40 + qd * 8;
  const short* rBu0 = sBu + (wc * 32 + l16) * 40 + qd * 8;

  for (int d0 = 0; d0 < D_DIM; d0 += 32) {
    short8 va = *(const short8*)(xa + d0);
    short8 vg = *(const short8*)(wga + d0);
    short8 vu = *(const short8*)(wua + d0);
    __syncthreads();
    *(short8*)wA = va;
    *(short8*)wBg = vg;
    *(short8*)wBu = vu;
    __syncthreads();
    short8 a0  = *(const short8*)rA0;
    short8 a1  = *(const short8*)(rA0 + 16 * 40);
    short8 bg0 = *(const short8*)rBg0;
    short8 bg1 = *(const short8*)(rBg0 + 16 * 40);
    short8 bu0 = *(const short8*)rBu0;
    short8 bu1 = *(const short8*)(rBu0 + 16 * 40);
    accG[0][0] = mfma16(a0, bg0, accG[0][0]);
    accG[0][1] = mfma16(a0, bg1, accG[0][1]);
    accG[1][0] = mfma16(a1, bg0, accG[1][0]);
    accG[1][1] = mfma16(a1, bg1, accG[1][1]);
    accU[0][0] = mfma16(a0, bu0, accU[0][0]);
    accU[0][1] = mfma16(a0, bu1, accU[0][1]);
    accU[1][0] = mfma16(a1, bu0, accU[1][0]);
    accU[1][1] = mfma16(a1, bu1, accU[1][1]);
  }
#pragma unroll
  for (int i = 0; i < 2; i++)
#pragma unroll
    for (int j = 0; j < 2; j++)
#pragma unroll
      for (int r = 0; r < 4; r++) {
        int rowl = wr * 32 + i * 16 + qd * 4 + r;
        int rowg = mt * 64 + rowl;
        if (rowg < count) {
          int raw2 = s_tok[rowl];
          int hrow = (raw2 & 0xFFFF) * 2 + (raw2 >> 16);
          int fc = f0 + wc * 32 + j * 16 + l16;
          float g = accG[i][j][r], u = accU[i][j][r];
          float sg = g / (1.f + __expf(-g));
          hbuf[(size_t)hrow * F_DIM + fc] = f2bf(sg * u * s_wt[rowl]);
        }
      }
}

// ---------------- GEMM2: y[token] += h[token,k] · Wd ---------------------------------
__global__ __launch_bounds__(256) void gemm2_kernel(
    const short* __restrict__ hbuf, const short* __restrict__ wdT,
    const int* __restrict__ counts, const int* __restrict__ tok_ids,
    float* __restrict__ outY) {
  int e = blockIdx.x >> 5;
  int mt = blockIdx.x & 31;
  int count = counts[e];
  if (mt * 64 >= count) return;
  int n0 = blockIdx.y * 64;

  __shared__ short sA[64 * 40];
  __shared__ short sB[64 * 40];
  __shared__ int s_tok[64];

  int tid = threadIdx.x;
  if (tid < 64) {
    int r = mt * 64 + tid;
    s_tok[tid] = (r < count) ? tok_ids[e * T_TOK + r] : 0;
  }
  int r4 = tid >> 2, ch = tid & 3;
  int lane = tid & 63, wv = tid >> 6;
  int wr = wv >> 1, wc = wv & 1;
  int qd = lane >> 4, l16 = lane & 15;

  floatx4 acc[2][2] = {};
  __syncthreads();
  int raw = s_tok[r4];
  int hrow = (raw & 0xFFFF) * 2 + (raw >> 16);
  const short* ha  = hbuf + (size_t)hrow * F_DIM + ch * 8;
  const short* wda = wdT + ((size_t)e * D_DIM + n0 + r4) * F_DIM + ch * 8;
  short* wA = sA + r4 * 40 + ch * 8;
  short* wB = sB + r4 * 40 + ch * 8;
  const short* rA0 = sA + (wr * 32 + l16) * 40 + qd * 8;
  const short* rB0 = sB + (wc * 32 + l16) * 40 + qd * 8;

  for (int f0 = 0; f0 < F_DIM; f0 += 32) {
    short8 va = *(const short8*)(ha + f0);
    short8 vb = *(const short8*)(wda + f0);
    __syncthreads();
    *(short8*)wA = va;
    *(short8*)wB = vb;
    __syncthreads();
    short8 a0 = *(const short8*)rA0;
    short8 a1 = *(const short8*)(rA0 + 16 * 40);
    short8 b0 = *(const short8*)rB0;
    short8 b1 = *(const short8*)(rB0 + 16 * 40);
    acc[0][0] = mfma16(a0, b0, acc[0][0]);
    acc[0][1] = mfma16(a0, b1, acc[0][1]);
    acc[1][0] = mfma16(a1, b0, acc[1][0]);
    acc[1][1] = mfma16(a1, b1, acc[1][1]);
  }
#pragma unroll
  for (int i = 0; i < 2; i++)
#pragma unroll
    for (int j = 0; j < 2; j++)
#pragma unroll
      for (int r = 0; r < 4; r++) {
        int rowl = wr * 32 + i * 16 + qd * 4 + r;
        int rowg = mt * 64 + rowl;
        if (rowg < count) {
          int tok = s_tok[rowl] & 0xFFFF;
          int nc = n0 + wc * 32 + j * 16 + l16;
          unsafeAtomicAdd(&outY[(size_t)tok * D_DIM + nc], acc[i][j][r]);
        }
      }
}

extern "C" void kernel_launch(void* const* d_in, const int* in_sizes, int n_in,
                              void* d_out, int out_size, void* d_ws, size_t ws_size,
                              hipStream_t stream) {
  (void)in_sizes; (void)n_in; (void)out_size; (void)ws_size;
  const float* hidden = (const float*)d_in[0];
  const float* gate_w = (const float*)d_in[1];
  const float* w_gate = (const float*)d_in[2];
  const float* w_up   = (const float*)d_in[3];
  const float* w_down = (const float*)d_in[4];
  float* out = (float*)d_out;
  float* outY = out;                                   // [T, D]
  float* outLogits = out + (size_t)T_TOK * D_DIM;      // [T, E]

  char* ws = (char*)d_ws;
  size_t off = 0;
  int* counts = (int*)(ws + off); off += 256;
  int* tok_ids = (int*)(ws + off); off += (size_t)N_EXP * T_TOK * 4;
  float* tok_wts = (float*)(ws + off); off += (size_t)N_EXP * T_TOK * 4;
  short* x_bf = (short*)(ws + off); off += (size_t)T_TOK * D_DIM * 2;
  short* wgT = (short*)(ws + off); off += (size_t)N_EXP * F_DIM * D_DIM * 2;
  short* wuT = (short*)(ws + off); off += (size_t)N_EXP * F_DIM * D_DIM * 2;
  short* wdT = (short*)(ws + off); off += (size_t)N_EXP * D_DIM * F_DIM * 2;
  short* hbuf = (short*)(ws + off); off += (size_t)T_TOK * 2 * F_DIM * 2;

  hipMemsetAsync(counts, 0, 256, stream);
  hipMemsetAsync(outY, 0, (size_t)T_TOK * D_DIM * 4, stream);

  // weights: [E][D][F] -> [E][F][D] (wg, wu), [E][F][D] -> [E][D][F] (wd)
  transpose_cvt<<<dim3(F_DIM / 32, D_DIM / 32, N_EXP), 256, 0, stream>>>(w_gate, wgT, D_DIM, F_DIM);
  transpose_cvt<<<dim3(F_DIM / 32, D_DIM / 32, N_EXP), 256, 0, stream>>>(w_up,   wuT, D_DIM, F_DIM);
  transpose_cvt<<<dim3(D_DIM / 32, F_DIM / 32, N_EXP), 256, 0, stream>>>(w_down, wdT, F_DIM, D_DIM);

  router_kernel<<<T_TOK, 256, 0, stream>>>(hidden, gate_w, x_bf, outLogits,
                                           counts, tok_ids, tok_wts);

  gemm1_kernel<<<dim3(N_EXP * 32, F_DIM / 64), 256, 0, stream>>>(
      x_bf, wgT, wuT, counts, tok_ids, tok_wts, hbuf);

  gemm2_kernel<<<dim3(N_EXP * 32, D_DIM / 64), 256, 0, stream>>>(
      hbuf, wdT, counts, tok_ids, outY);
}

// Round 3
// 497.015 us; speedup vs baseline: 1.4184x; 1.4184x over previous
//
#include <hip/hip_runtime.h>
#include <hip/hip_bf16.h>

#define T_TOK 2048
#define D_DIM 2048
#define N_EXP 8
#define F_DIM 1024

typedef __attribute__((ext_vector_type(8))) short short8;
typedef __attribute__((ext_vector_type(4))) float floatx4;

__device__ __forceinline__ short f2bf(float f) {
  union { float f; unsigned u; } v; v.f = f;
  unsigned r = v.u + 0x7fffu + ((v.u >> 16) & 1u);
  return (short)(r >> 16);
}

__device__ __forceinline__ floatx4 mfma16(short8 a, short8 b, floatx4 c) {
  return __builtin_amdgcn_mfma_f32_16x16x32_bf16(a, b, c, 0, 0, 0);
}

__device__ __forceinline__ void gload16(const void* g, void* l) {
  __builtin_amdgcn_global_load_lds(
      (const __attribute__((address_space(1))) unsigned int*)g,
      (__attribute__((address_space(3))) unsigned int*)l, 16, 0, 0);
}

// ---------------- transpose + fp32->bf16 convert: dst[c][r] = src[r][c] per expert ----
__global__ __launch_bounds__(256) void transpose_cvt(const float* __restrict__ src,
                                                     short* __restrict__ dst,
                                                     int R, int C) {
  __shared__ float tile[32][33];
  int e = blockIdx.z;
  src += (size_t)e * R * C;
  dst += (size_t)e * R * C;
  int c0 = blockIdx.x * 32, r0 = blockIdx.y * 32;
  int tx = threadIdx.x & 31, ty = threadIdx.x >> 5;
#pragma unroll
  for (int i = 0; i < 32; i += 8)
    tile[ty + i][tx] = src[(size_t)(r0 + ty + i) * C + c0 + tx];
  __syncthreads();
#pragma unroll
  for (int i = 0; i < 32; i += 8)
    dst[(size_t)(c0 + ty + i) * R + r0 + tx] = f2bf(tile[tx][ty + i]);
}

// ---------------- router: logits (fp32), top-2, expert lists, x -> bf16 --------------
__global__ __launch_bounds__(256) void router_kernel(
    const float* __restrict__ x, const float* __restrict__ gate_w,
    short* __restrict__ x_bf, float* __restrict__ out_logits,
    int* __restrict__ counts, int* __restrict__ tok_ids, float* __restrict__ tok_wts) {
  int t = blockIdx.x;
  int tid = threadIdx.x;
  const float* xr = x + (size_t)t * D_DIM + tid * 8;
  floatx4 xv0 = *(const floatx4*)xr;
  floatx4 xv1 = *(const floatx4*)(xr + 4);
  float xs[8];
#pragma unroll
  for (int j = 0; j < 4; j++) { xs[j] = xv0[j]; xs[4 + j] = xv1[j]; }
  union { short8 v; short s[8]; } xb;
#pragma unroll
  for (int j = 0; j < 8; j++) xb.s[j] = f2bf(xs[j]);
  *(short8*)(x_bf + (size_t)t * D_DIM + tid * 8) = xb.v;

  float p[N_EXP];
#pragma unroll
  for (int e = 0; e < N_EXP; e++) {
    const float* gw = gate_w + (size_t)e * D_DIM + tid * 8;
    floatx4 g0 = *(const floatx4*)gw;
    floatx4 g1 = *(const floatx4*)(gw + 4);
    float s = 0.f;
#pragma unroll
    for (int j = 0; j < 4; j++) s += xs[j] * g0[j] + xs[4 + j] * g1[j];
    p[e] = s;
  }
  __shared__ float red[N_EXP * 4];
  __shared__ float slog[N_EXP];
  int lane = tid & 63, wv = tid >> 6;
#pragma unroll
  for (int e = 0; e < N_EXP; e++) {
    float v = p[e];
#pragma unroll
    for (int off = 32; off > 0; off >>= 1) v += __shfl_down(v, off);
    if (lane == 0) red[e * 4 + wv] = v;
  }
  __syncthreads();
  if (tid < N_EXP) {
    float s = red[tid * 4] + red[tid * 4 + 1] + red[tid * 4 + 2] + red[tid * 4 + 3];
    slog[tid] = s;
    out_logits[(size_t)t * N_EXP + tid] = s;
  }
  __syncthreads();
  if (tid == 0) {
    float l[N_EXP];
#pragma unroll
    for (int e = 0; e < N_EXP; e++) l[e] = slog[e];
    int e0 = 0;
#pragma unroll
    for (int e = 1; e < N_EXP; e++) if (l[e] > l[e0]) e0 = e;
    int e1 = (e0 == 0) ? 1 : 0;
#pragma unroll
    for (int e = 0; e < N_EXP; e++) if (e != e0 && l[e] > l[e1]) e1 = e;
    float p1 = __expf(l[e1] - l[e0]);
    float s = 1.f + p1;
    int pos0 = atomicAdd(&counts[e0], 1);
    tok_ids[e0 * T_TOK + pos0] = t;             // k = 0
    tok_wts[e0 * T_TOK + pos0] = 1.f / s;
    int pos1 = atomicAdd(&counts[e1], 1);
    tok_ids[e1 * T_TOK + pos1] = t | (1 << 16); // k = 1
    tok_wts[e1 * T_TOK + pos1] = p1 / s;
  }
}

// ---------------- GEMM1: 128x128 tile, BK=64, global_load_lds + XOR swizzle ----------
// Staging: per it-step each wave stages 8 rows (lr=lane>>3) x 8 chunks (lc=lane&7);
// global chunk index is XOR-swizzled (lc^lr) so LDS[row][pos] = chunk(pos ^ (row&7)).
// h[token*2+k][f] = silu(x Wg) * (x Wu) * route_w
__global__ __launch_bounds__(256, 2) void gemm1_kernel(
    const short* __restrict__ x_bf,
    const short* __restrict__ wgT, const short* __restrict__ wuT,
    const int* __restrict__ counts, const int* __restrict__ tok_ids,
    const float* __restrict__ tok_wts,
    short* __restrict__ hbuf) {
  int e = blockIdx.x >> 4;
  int mt = blockIdx.x & 15;
  int count = counts[e];
  if (mt * 128 >= count) return;
  int f0 = blockIdx.y * 128;

  __shared__ short sA[128 * 64];
  __shared__ short sBg[128 * 64];
  __shared__ short sBu[128 * 64];
  __shared__ int s_tok[128];
  __shared__ float s_wt[128];

  int tid = threadIdx.x;
  if (tid < 128) {
    int r = mt * 128 + tid;
    if (r < count) { s_tok[tid] = tok_ids[e * T_TOK + r]; s_wt[tid] = tok_wts[e * T_TOK + r]; }
    else { s_tok[tid] = 0; s_wt[tid] = 0.f; }
  }
  __syncthreads();

  int lane = tid & 63, wv = tid >> 6;
  int wr = wv >> 1, wc = wv & 1;
  int l16 = lane & 15, qd = lane >> 4;
  int lr = lane >> 3, lc = lane & 7;
  int csw8 = (lc ^ lr) * 8;   // XOR swizzle: global chunk this lane stages

  int offA[4], offB[4];
#pragma unroll
  for (int it = 0; it < 4; it++) {
    int r = wv * 32 + it * 8 + lr;                    // 8 rows per wave per it
    offA[it] = (s_tok[r] & 0xFFFF) * D_DIM + csw8;
    offB[it] = (e * F_DIM + f0 + r) * D_DIM + csw8;   // same offset for wg and wu
  }
  short* sdA  = sA  + wv * 2048;   // wave-uniform LDS base; HW adds lane*16B
  short* sdBg = sBg + wv * 2048;
  short* sdBu = sBu + wv * 2048;

  floatx4 accG[4][4] = {};
  floatx4 accU[4][4] = {};

  const short* rA  = sA  + (wr * 64 + l16) * 64;
  const short* rBg = sBg + (wc * 64 + l16) * 64;
  const short* rBu = sBu + (wc * 64 + l16) * 64;
  int sw = l16 & 7;

  for (int d0 = 0; d0 < D_DIM; d0 += 64) {
    __syncthreads();
#pragma unroll
    for (int it = 0; it < 4; it++) {
      gload16(x_bf + offA[it] + d0, sdA  + it * 512);
      gload16(wgT  + offB[it] + d0, sdBg + it * 512);
      gload16(wuT  + offB[it] + d0, sdBu + it * 512);
    }
    __syncthreads();
#pragma unroll
    for (int kk = 0; kk < 2; kk++) {
      short8 a[4], bg[4], bu[4];
      int c = ((kk * 4 + qd) ^ sw) * 8;
#pragma unroll
      for (int mi = 0; mi < 4; mi++) a[mi] = *(const short8*)(rA + mi * 16 * 64 + c);
#pragma unroll
      for (int nj = 0; nj < 4; nj++) {
        bg[nj] = *(const short8*)(rBg + nj * 16 * 64 + c);
        bu[nj] = *(const short8*)(rBu + nj * 16 * 64 + c);
      }
#pragma unroll
      for (int mi = 0; mi < 4; mi++)
#pragma unroll
        for (int nj = 0; nj < 4; nj++) {
          accG[mi][nj] = mfma16(a[mi], bg[nj], accG[mi][nj]);
          accU[mi][nj] = mfma16(a[mi], bu[nj], accU[mi][nj]);
        }
    }
  }

#pragma unroll
  for (int mi = 0; mi < 4; mi++)
#pragma unroll
    for (int r = 0; r < 4; r++) {
      int rowl = wr * 64 + mi * 16 + qd * 4 + r;
      if (mt * 128 + rowl < count) {
        int raw = s_tok[rowl];
        int hrow = (raw & 0xFFFF) * 2 + (raw >> 16);
        float wt = s_wt[rowl];
        short* hdst = hbuf + (size_t)hrow * F_DIM + f0 + wc * 64 + l16;
#pragma unroll
        for (int nj = 0; nj < 4; nj++) {
          float g = accG[mi][nj][r], u = accU[mi][nj][r];
          float sg = g / (1.f + __expf(-g));
          hdst[nj * 16] = f2bf(sg * u * wt);
        }
      }
    }
}

// ---------------- GEMM2: 128x128 tile, BK=64: y[token] += h[token,k] . Wd ------------
__global__ __launch_bounds__(256, 2) void gemm2_kernel(
    const short* __restrict__ hbuf, const short* __restrict__ wdT,
    const int* __restrict__ counts, const int* __restrict__ tok_ids,
    float* __restrict__ outY) {
  int e = blockIdx.x >> 4;
  int mt = blockIdx.x & 15;
  int count = counts[e];
  if (mt * 128 >= count) return;
  int n0 = blockIdx.y * 128;

  __shared__ short sA[128 * 64];
  __shared__ short sB[128 * 64];
  __shared__ int s_tok[128];

  int tid = threadIdx.x;
  if (tid < 128) {
    int r = mt * 128 + tid;
    s_tok[tid] = (r < count) ? tok_ids[e * T_TOK + r] : 0;
  }
  __syncthreads();

  int lane = tid & 63, wv = tid >> 6;
  int wr = wv >> 1, wc = wv & 1;
  int l16 = lane & 15, qd = lane >> 4;
  int lr = lane >> 3, lc = lane & 7;
  int csw8 = (lc ^ lr) * 8;

  int offA[4], offB[4];
#pragma unroll
  for (int it = 0; it < 4; it++) {
    int r = wv * 32 + it * 8 + lr;                    // 8 rows per wave per it
    int raw = s_tok[r];
    offA[it] = ((raw & 0xFFFF) * 2 + (raw >> 16)) * F_DIM + csw8;
    offB[it] = (e * D_DIM + n0 + r) * F_DIM + csw8;
  }
  short* sdA = sA + wv * 2048;   // wave-uniform LDS base; HW adds lane*16B
  short* sdB = sB + wv * 2048;

  floatx4 acc[4][4] = {};

  const short* rA = sA + (wr * 64 + l16) * 64;
  const short* rB = sB + (wc * 64 + l16) * 64;
  int sw = l16 & 7;

  for (int k0 = 0; k0 < F_DIM; k0 += 64) {
    __syncthreads();
#pragma unroll
    for (int it = 0; it < 4; it++) {
      gload16(hbuf + offA[it] + k0, sdA + it * 512);
      gload16(wdT  + offB[it] + k0, sdB + it * 512);
    }
    __syncthreads();
#pragma unroll
    for (int kk = 0; kk < 2; kk++) {
      short8 a[4], b[4];
      int c = ((kk * 4 + qd) ^ sw) * 8;
#pragma unroll
      for (int mi = 0; mi < 4; mi++) a[mi] = *(const short8*)(rA + mi * 16 * 64 + c);
#pragma unroll
      for (int nj = 0; nj < 4; nj++) b[nj] = *(const short8*)(rB + nj * 16 * 64 + c);
#pragma unroll
      for (int mi = 0; mi < 4; mi++)
#pragma unroll
        for (int nj = 0; nj < 4; nj++)
          acc[mi][nj] = mfma16(a[mi], b[nj], acc[mi][nj]);
    }
  }

#pragma unroll
  for (int mi = 0; mi < 4; mi++)
#pragma unroll
    for (int r = 0; r < 4; r++) {
      int rowl = wr * 64 + mi * 16 + qd * 4 + r;
      if (mt * 128 + rowl < count) {
        int tok = s_tok[rowl] & 0xFFFF;
        float* dst = outY + (size_t)tok * D_DIM + n0 + wc * 64 + l16;
#pragma unroll
        for (int nj = 0; nj < 4; nj++)
          unsafeAtomicAdd(&dst[nj * 16], acc[mi][nj][r]);
      }
    }
}

extern "C" void kernel_launch(void* const* d_in, const int* in_sizes, int n_in,
                              void* d_out, int out_size, void* d_ws, size_t ws_size,
                              hipStream_t stream) {
  (void)in_sizes; (void)n_in; (void)out_size; (void)ws_size;
  const float* hidden = (const float*)d_in[0];
  const float* gate_w = (const float*)d_in[1];
  const float* w_gate = (const float*)d_in[2];
  const float* w_up   = (const float*)d_in[3];
  const float* w_down = (const float*)d_in[4];
  float* out = (float*)d_out;
  float* outY = out;                                   // [T, D]
  float* outLogits = out + (size_t)T_TOK * D_DIM;      // [T, E]

  char* ws = (char*)d_ws;
  size_t off = 0;
  int* counts = (int*)(ws + off); off += 256;
  int* tok_ids = (int*)(ws + off); off += (size_t)N_EXP * T_TOK * 4;
  float* tok_wts = (float*)(ws + off); off += (size_t)N_EXP * T_TOK * 4;
  short* x_bf = (short*)(ws + off); off += (size_t)T_TOK * D_DIM * 2;
  short* wgT = (short*)(ws + off); off += (size_t)N_EXP * F_DIM * D_DIM * 2;
  short* wuT = (short*)(ws + off); off += (size_t)N_EXP * F_DIM * D_DIM * 2;
  short* wdT = (short*)(ws + off); off += (size_t)N_EXP * D_DIM * F_DIM * 2;
  short* hbuf = (short*)(ws + off); off += (size_t)T_TOK * 2 * F_DIM * 2;

  hipMemsetAsync(counts, 0, 256, stream);
  hipMemsetAsync(outY, 0, (size_t)T_TOK * D_DIM * 4, stream);

  // weights: [E][D][F] -> [E][F][D] (wg, wu), [E][F][D] -> [E][D][F] (wd)
  transpose_cvt<<<dim3(F_DIM / 32, D_DIM / 32, N_EXP), 256, 0, stream>>>(w_gate, wgT, D_DIM, F_DIM);
  transpose_cvt<<<dim3(F_DIM / 32, D_DIM / 32, N_EXP), 256, 0, stream>>>(w_up,   wuT, D_DIM, F_DIM);
  transpose_cvt<<<dim3(D_DIM / 32, F_DIM / 32, N_EXP), 256, 0, stream>>>(w_down, wdT, F_DIM, D_DIM);

  router_kernel<<<T_TOK, 256, 0, stream>>>(hidden, gate_w, x_bf, outLogits,
                                           counts, tok_ids, tok_wts);

  gemm1_kernel<<<dim3(N_EXP * 16, F_DIM / 128), 256, 0, stream>>>(
      x_bf, wgT, wuT, counts, tok_ids, tok_wts, hbuf);

  gemm2_kernel<<<dim3(N_EXP * 16, D_DIM / 128), 256, 0, stream>>>(
      hbuf, wdT, counts, tok_ids, outY);
}